// Round 5
// baseline (278.474 us; speedup 1.0000x reference)
//
#include <hip/hip_runtime.h>
#include <math.h>

#define H 256
#define TILE 256
#define NBLK 512    // gather grid (= number of 256-event tiles)
#define NABC 256    // bucketize grid: 1 block/CU, co-resident -> barriers safe
#define NBKT 512    // buckets = loc>>8 (loc < 131072 covered)

// ws layout (float offsets):
//   [0..63]       hdr: barrier counter hdr[0], scan-done flag hdr[32]
//   [64..575]     cur[512] (int): histogram -> exclusive scan -> cursors
//   [576..1599]   v[4][H]
//   [1600..2367]  pqu[3][H]
//   [4096..]      ev_loc[L] (int)
//   [4096+L..]    ev_w[L] (float4, 16B aligned for L mult of 4)
// memset covers bytes [0 .. 6400): hdr + cur + v.

typedef unsigned u32;

// ---------------------------------------------------------------------------
// Kernel 1 (fused A/B/C): bucketize events by table-row locality.
//   A: per-block LDS histogram of loc>>8, flushed with global atomics
//   B: (block 0) exclusive scan of the 512 bins -> cursors
//   C: scatter (loc, w0..w3) into bucket-dense ev arrays via cursor atomics
// 256 blocks = 1/CU, all co-resident: spin barriers cannot deadlock.
// ---------------------------------------------------------------------------
__global__ __launch_bounds__(256) void strnn_bucketize(
    const float* __restrict__ td_u, const float* __restrict__ td_l,
    const float* __restrict__ ld_u, const float* __restrict__ ld_l,
    const int* __restrict__ loc, u32* __restrict__ hdr, int* __restrict__ cur,
    int* __restrict__ ev_loc, float4* __restrict__ ev_w, int L)
{
    __shared__ int s_h[NBKT];
    const int t = threadIdx.x;

    // ---- A: LDS histogram ----
    #pragma unroll
    for (int i = t; i < NBKT; i += 256) s_h[i] = 0;
    __syncthreads();
    for (int i = blockIdx.x * 256 + t; i < L; i += NABC * 256)
        atomicAdd(&s_h[((u32)loc[i]) >> 8], 1);
    __syncthreads();
    #pragma unroll
    for (int i = t; i < NBKT; i += 256) {
        const int c = s_h[i];
        if (c) atomicAdd(&cur[i], c);
    }

    // ---- barrier 1: all histogram contributions done ----
    __threadfence();
    __syncthreads();
    if (t == 0)
        __hip_atomic_fetch_add(&hdr[0], 1u, __ATOMIC_RELEASE,
                               __HIP_MEMORY_SCOPE_AGENT);
    if (blockIdx.x == 0) {
        if (t == 0)
            while (__hip_atomic_load(&hdr[0], __ATOMIC_ACQUIRE,
                                     __HIP_MEMORY_SCOPE_AGENT) < NABC)
                __builtin_amdgcn_s_sleep(1);
        __syncthreads();

        // ---- B: exclusive scan of cur[0..511] (block 0 only) ----
        #pragma unroll
        for (int i = t; i < NBKT; i += 256)
            s_h[i] = __hip_atomic_load(&cur[i], __ATOMIC_RELAXED,
                                       __HIP_MEMORY_SCOPE_AGENT);
        __syncthreads();
        for (int off = 1; off < NBKT; off <<= 1) {
            const int i0 = t, i1 = t + 256;
            const int a0 = (i0 >= off) ? s_h[i0 - off] : 0;
            const int a1 = (i1 >= off) ? s_h[i1 - off] : 0;
            __syncthreads();
            s_h[i0] += a0;
            s_h[i1] += a1;
            __syncthreads();
        }
        #pragma unroll
        for (int i = t; i < NBKT; i += 256)
            __hip_atomic_store(&cur[i], i ? s_h[i - 1] : 0, __ATOMIC_RELAXED,
                               __HIP_MEMORY_SCOPE_AGENT);
        __threadfence();
        __syncthreads();
        if (t == 0)
            __hip_atomic_store(&hdr[32], 1u, __ATOMIC_RELEASE,
                               __HIP_MEMORY_SCOPE_AGENT);
    } else {
        if (t == 0)
            while (__hip_atomic_load(&hdr[32], __ATOMIC_ACQUIRE,
                                     __HIP_MEMORY_SCOPE_AGENT) == 0)
                __builtin_amdgcn_s_sleep(1);
    }
    __syncthreads();

    // ---- C: scatter events into bucket-dense order ----
    for (int i = blockIdx.x * 256 + t; i < L; i += NABC * 256) {
        const float tu = fminf(fmaxf(td_u[i], 0.f), 1440.f);
        const float tl = fminf(fmaxf(td_l[i], 0.f), 1440.f);
        const float lu = fminf(fmaxf(ld_u[i], 0.f), 40.f);
        const float ll = fminf(fmaxf(ld_l[i], 0.f), 40.f);
        const float al = tu / (tu + tl);
        const float be = lu / (lu + ll);
        const int r = loc[i];
        const int pos = atomicAdd(&cur[((u32)r) >> 8], 1);
        ev_loc[pos] = r;
        ev_w[pos] = make_float4(be * al, be * (1.f - al),
                                (1.f - be) * al, (1.f - be) * (1.f - al));
    }
}

// ---------------------------------------------------------------------------
// Kernel 2: gather — round-0 inner loop verbatim, but the event stream is
// bucket-ordered: a 256-event tile touches a ~256-512 KB table window
// (DRAM page reuse; duplicate rows become L2/L3 hits) instead of a random
// 100K-row spray. Tail: LDS cross-wave reduce + 4 atomicAdds/thread
// (proven ~free in r0).
// ---------------------------------------------------------------------------
__global__ __launch_bounds__(256) void strnn_gather(
    const int* __restrict__ ev_loc, const float4* __restrict__ ev_w,
    const float* __restrict__ table, float* __restrict__ v, int L)
{
    __shared__ float4 s_w[TILE];       //  4 KB
    __shared__ int    s_loc[TILE];     //  1 KB
    __shared__ float  s_red[4][4][H];  // 16 KB
    const int t    = threadIdx.x;
    const int wave = t >> 6;
    const int lane = t & 63;

    float4 a0 = {0,0,0,0}, a1 = {0,0,0,0}, a2 = {0,0,0,0}, a3 = {0,0,0,0};

    for (int base = blockIdx.x * TILE; base < L; base += gridDim.x * TILE) {
        const int l = base + t;
        const bool ok = (l < L);
        s_w[t]   = ok ? ev_w[l] : make_float4(0.f, 0.f, 0.f, 0.f);
        s_loc[t] = ok ? ev_loc[l] : 0;
        __syncthreads();

        const int r0 = wave * 64;
        #pragma unroll 2
        for (int j = 0; j < 64; j += 8) {
            const float4* addr[8];
            #pragma unroll
            for (int u = 0; u < 8; ++u)
                addr[u] = (const float4*)(table + (size_t)s_loc[r0 + j + u] * H + 4 * lane);
            float4 w[8], e[8];
            #pragma unroll
            for (int u = 0; u < 8; ++u)
                e[u] = *addr[u];                 // 8 loads in flight
            #pragma unroll
            for (int u = 0; u < 8; ++u)
                w[u] = s_w[r0 + j + u];          // broadcast ds_read_b128
            #pragma unroll
            for (int u = 0; u < 8; ++u) {
                a0.x = fmaf(w[u].x, e[u].x, a0.x);
                a0.y = fmaf(w[u].x, e[u].y, a0.y);
                a0.z = fmaf(w[u].x, e[u].z, a0.z);
                a0.w = fmaf(w[u].x, e[u].w, a0.w);
                a1.x = fmaf(w[u].y, e[u].x, a1.x);
                a1.y = fmaf(w[u].y, e[u].y, a1.y);
                a1.z = fmaf(w[u].y, e[u].z, a1.z);
                a1.w = fmaf(w[u].y, e[u].w, a1.w);
                a2.x = fmaf(w[u].z, e[u].x, a2.x);
                a2.y = fmaf(w[u].z, e[u].y, a2.y);
                a2.z = fmaf(w[u].z, e[u].z, a2.z);
                a2.w = fmaf(w[u].z, e[u].w, a2.w);
                a3.x = fmaf(w[u].w, e[u].x, a3.x);
                a3.y = fmaf(w[u].w, e[u].y, a3.y);
                a3.z = fmaf(w[u].w, e[u].z, a3.z);
                a3.w = fmaf(w[u].w, e[u].w, a3.w);
            }
        }
        __syncthreads();
    }

    *(float4*)&s_red[wave][0][4 * lane] = a0;
    *(float4*)&s_red[wave][1][4 * lane] = a1;
    *(float4*)&s_red[wave][2][4 * lane] = a2;
    *(float4*)&s_red[wave][3][4 * lane] = a3;
    __syncthreads();
    #pragma unroll
    for (int c = 0; c < 4; ++c) {
        float s = s_red[0][c][t] + s_red[1][c][t] + s_red[2][c][t] + s_red[3][c][t];
        atomicAdd(&v[c * H + t], s);
    }
}

// Kernel 3: one wave per output row h (r0 verbatim).
__global__ __launch_bounds__(256) void strnn_mid(
    const float* __restrict__ Wtu, const float* __restrict__ Wtl,
    const float* __restrict__ Wih, const float* __restrict__ hx,
    const float* __restrict__ v, float* __restrict__ pqu)
{
    const int wave = (blockIdx.x * blockDim.x + threadIdx.x) >> 6;  // = h
    const int lane = threadIdx.x & 63;
    const float* v1 = v;
    const float* v2 = v + H;
    const float* v3 = v + 2 * H;
    const float* v4 = v + 3 * H;

    float p = 0.f, q = 0.f, u = 0.f;
    #pragma unroll
    for (int i = 0; i < H; i += 64) {
        const int k = i + lane;
        const float wtu = Wtu[wave * H + k];
        const float wtl = Wtl[wave * H + k];
        p = fmaf(wtu, v1[k], fmaf(wtl, v2[k], p));
        q = fmaf(wtu, v3[k], fmaf(wtl, v4[k], q));
        u = fmaf(Wih[wave * H + k], hx[k], u);
    }
    #pragma unroll
    for (int off = 32; off > 0; off >>= 1) {
        p += __shfl_down(p, off, 64);
        q += __shfl_down(q, off, 64);
        u += __shfl_down(u, off, 64);
    }
    if (lane == 0) {
        pqu[wave]         = p;
        pqu[H + wave]     = q;
        pqu[2 * H + wave] = u;
    }
}

// Kernel 4: out[h] = sigmoid( Wsu[h,:]·p + Wsl[h,:]·q + u[h] )  (r0 verbatim).
__global__ __launch_bounds__(256) void strnn_out(
    const float* __restrict__ Wsu, const float* __restrict__ Wsl,
    const float* __restrict__ pqu, float* __restrict__ out)
{
    const int wave = (blockIdx.x * blockDim.x + threadIdx.x) >> 6;  // = h
    const int lane = threadIdx.x & 63;
    const float* p = pqu;
    const float* q = pqu + H;
    const float* u = pqu + 2 * H;

    float s = 0.f;
    #pragma unroll
    for (int i = 0; i < H; i += 64) {
        const int k = i + lane;
        s = fmaf(Wsu[wave * H + k], p[k], fmaf(Wsl[wave * H + k], q[k], s));
    }
    #pragma unroll
    for (int off = 32; off > 0; off >>= 1)
        s += __shfl_down(s, off, 64);
    if (lane == 0)
        out[wave] = 1.f / (1.f + expf(-(s + u[wave])));
}

extern "C" void kernel_launch(void* const* d_in, const int* in_sizes, int n_in,
                              void* d_out, int out_size, void* d_ws, size_t ws_size,
                              hipStream_t stream) {
    const float* td_u  = (const float*)d_in[0];
    const float* td_l  = (const float*)d_in[1];
    const float* ld_u  = (const float*)d_in[2];
    const float* ld_l  = (const float*)d_in[3];
    const int*   loc   = (const int*)d_in[4];
    const float* hx    = (const float*)d_in[5];
    const float* Wih   = (const float*)d_in[6];
    const float* Wtu   = (const float*)d_in[7];
    const float* Wtl   = (const float*)d_in[8];
    const float* Wsu   = (const float*)d_in[9];
    const float* Wsl   = (const float*)d_in[10];
    const float* table = (const float*)d_in[11];
    const int L = in_sizes[0];

    float*  ws     = (float*)d_ws;
    u32*    hdr    = (u32*)ws;                    // [0..63]
    int*    cur    = (int*)(ws + 64);             // [512]
    float*  v      = ws + 576;                    // 4*H
    float*  pqu    = ws + 1600;                   // 3*H
    int*    ev_loc = (int*)(ws + 4096);           // L ints
    float4* ev_w   = (float4*)(ws + 4096 + L);    // L float4 (16B aligned)

    // zero hdr + cur + v (6.4 KB) — ws is re-poisoned before every launch
    hipMemsetAsync(ws, 0, 6400, stream);

    strnn_bucketize<<<NABC, 256, 0, stream>>>(
        td_u, td_l, ld_u, ld_l, loc, hdr, cur, ev_loc, ev_w, L);
    strnn_gather<<<NBLK, 256, 0, stream>>>(ev_loc, ev_w, table, v, L);
    strnn_mid<<<64, 256, 0, stream>>>(Wtu, Wtl, Wih, hx, v, pqu);
    strnn_out<<<64, 256, 0, stream>>>(Wsu, Wsl, pqu, (float*)d_out);
}

// Round 6
// 195.090 us; speedup vs baseline: 1.4274x; 1.4274x over previous
//
#include <hip/hip_runtime.h>
#include <math.h>

#define H 256
#define TILE 128    // events per block-tile (was 256)
#define NBLK 1024   // gather grid (was 512) -> 4 blocks/CU, 16 waves/CU

// Kernel 1: v[c][h] = sum_l w_c(l) * table[loc[l]][h], c = 0..3
// r0 structure, occupancy-doubled: wave owns 32 rows of the block's 128-row
// tile; 8 rows' 1KB loads in flight per wave; 4 blocks/CU resident (vs 2)
// -> 2x outstanding memory to cover the ~900cy gather latency the sorted-
// input experiment (r5) proved is the real limiter.
__global__ __launch_bounds__(256) void strnn_gather(
    const float* __restrict__ td_u, const float* __restrict__ td_l,
    const float* __restrict__ ld_u, const float* __restrict__ ld_l,
    const int* __restrict__ loc, const float* __restrict__ table,
    float* __restrict__ v, int L)
{
    __shared__ float4 s_w[TILE];       //  2 KB
    __shared__ int    s_loc[TILE];     //  0.5 KB
    __shared__ float  s_red[4][4][H];  // 16 KB: [wave][c][col]
    const int t    = threadIdx.x;
    const int wave = t >> 6;
    const int lane = t & 63;

    float4 a0 = {0,0,0,0}, a1 = {0,0,0,0}, a2 = {0,0,0,0}, a3 = {0,0,0,0};

    for (int base = blockIdx.x * TILE; base < L; base += gridDim.x * TILE) {
        if (t < TILE) {
            const int l = base + t;
            const bool ok = (l < L);
            float tu = ok ? fminf(fmaxf(td_u[l], 0.f), 1440.f) : 1.f;
            float tl = ok ? fminf(fmaxf(td_l[l], 0.f), 1440.f) : 1.f;
            float lu = ok ? fminf(fmaxf(ld_u[l], 0.f), 40.f)   : 1.f;
            float ll = ok ? fminf(fmaxf(ld_l[l], 0.f), 40.f)   : 1.f;
            float al = tu / (tu + tl);
            float be = lu / (lu + ll);
            float w0 = be * al, w1 = be * (1.f - al);
            float w2 = (1.f - be) * al, w3 = (1.f - be) * (1.f - al);
            if (!ok) { w0 = w1 = w2 = w3 = 0.f; }
            s_w[t]   = make_float4(w0, w1, w2, w3);
            s_loc[t] = ok ? loc[l] : 0;
        }
        __syncthreads();

        const int r0 = wave * 32;
        #pragma unroll 2
        for (int j = 0; j < 32; j += 8) {
            const float4* addr[8];
            #pragma unroll
            for (int u = 0; u < 8; ++u)
                addr[u] = (const float4*)(table + (size_t)s_loc[r0 + j + u] * H + 4 * lane);
            float4 w[8], e[8];
            #pragma unroll
            for (int u = 0; u < 8; ++u)
                e[u] = *addr[u];                 // 8 loads in flight
            #pragma unroll
            for (int u = 0; u < 8; ++u)
                w[u] = s_w[r0 + j + u];          // broadcast ds_read_b128
            #pragma unroll
            for (int u = 0; u < 8; ++u) {
                a0.x = fmaf(w[u].x, e[u].x, a0.x);
                a0.y = fmaf(w[u].x, e[u].y, a0.y);
                a0.z = fmaf(w[u].x, e[u].z, a0.z);
                a0.w = fmaf(w[u].x, e[u].w, a0.w);
                a1.x = fmaf(w[u].y, e[u].x, a1.x);
                a1.y = fmaf(w[u].y, e[u].y, a1.y);
                a1.z = fmaf(w[u].y, e[u].z, a1.z);
                a1.w = fmaf(w[u].y, e[u].w, a1.w);
                a2.x = fmaf(w[u].z, e[u].x, a2.x);
                a2.y = fmaf(w[u].z, e[u].y, a2.y);
                a2.z = fmaf(w[u].z, e[u].z, a2.z);
                a2.w = fmaf(w[u].z, e[u].w, a2.w);
                a3.x = fmaf(w[u].w, e[u].x, a3.x);
                a3.y = fmaf(w[u].w, e[u].y, a3.y);
                a3.z = fmaf(w[u].w, e[u].z, a3.z);
                a3.w = fmaf(w[u].w, e[u].w, a3.w);
            }
        }
        __syncthreads();
    }

    // cross-wave block reduction in LDS, then 4 atomicAdds per thread
    // (overlaps with still-running blocks; proven ~free in r0/r4)
    *(float4*)&s_red[wave][0][4 * lane] = a0;
    *(float4*)&s_red[wave][1][4 * lane] = a1;
    *(float4*)&s_red[wave][2][4 * lane] = a2;
    *(float4*)&s_red[wave][3][4 * lane] = a3;
    __syncthreads();
    #pragma unroll
    for (int c = 0; c < 4; ++c) {
        float s = s_red[0][c][t] + s_red[1][c][t] + s_red[2][c][t] + s_red[3][c][t];
        atomicAdd(&v[c * H + t], s);
    }
}

// Kernel 2: one wave per output row h (r0 verbatim):
//   p[h] = Wtu[h,:]·v1 + Wtl[h,:]·v2
//   q[h] = Wtu[h,:]·v3 + Wtl[h,:]·v4
//   u[h] = Wih[h,:]·hx
__global__ __launch_bounds__(256) void strnn_mid(
    const float* __restrict__ Wtu, const float* __restrict__ Wtl,
    const float* __restrict__ Wih, const float* __restrict__ hx,
    const float* __restrict__ v, float* __restrict__ pqu)
{
    const int wave = (blockIdx.x * blockDim.x + threadIdx.x) >> 6;  // = h
    const int lane = threadIdx.x & 63;
    const float* v1 = v;
    const float* v2 = v + H;
    const float* v3 = v + 2 * H;
    const float* v4 = v + 3 * H;

    float p = 0.f, q = 0.f, u = 0.f;
    #pragma unroll
    for (int i = 0; i < H; i += 64) {
        const int k = i + lane;
        const float wtu = Wtu[wave * H + k];
        const float wtl = Wtl[wave * H + k];
        p = fmaf(wtu, v1[k], fmaf(wtl, v2[k], p));
        q = fmaf(wtu, v3[k], fmaf(wtl, v4[k], q));
        u = fmaf(Wih[wave * H + k], hx[k], u);
    }
    #pragma unroll
    for (int off = 32; off > 0; off >>= 1) {
        p += __shfl_down(p, off, 64);
        q += __shfl_down(q, off, 64);
        u += __shfl_down(u, off, 64);
    }
    if (lane == 0) {
        pqu[wave]         = p;
        pqu[H + wave]     = q;
        pqu[2 * H + wave] = u;
    }
}

// Kernel 3: out[h] = sigmoid( Wsu[h,:]·p + Wsl[h,:]·q + u[h] )  (r0 verbatim)
__global__ __launch_bounds__(256) void strnn_out(
    const float* __restrict__ Wsu, const float* __restrict__ Wsl,
    const float* __restrict__ pqu, float* __restrict__ out)
{
    const int wave = (blockIdx.x * blockDim.x + threadIdx.x) >> 6;  // = h
    const int lane = threadIdx.x & 63;
    const float* p = pqu;
    const float* q = pqu + H;
    const float* u = pqu + 2 * H;

    float s = 0.f;
    #pragma unroll
    for (int i = 0; i < H; i += 64) {
        const int k = i + lane;
        s = fmaf(Wsu[wave * H + k], p[k], fmaf(Wsl[wave * H + k], q[k], s));
    }
    #pragma unroll
    for (int off = 32; off > 0; off >>= 1)
        s += __shfl_down(s, off, 64);
    if (lane == 0)
        out[wave] = 1.f / (1.f + expf(-(s + u[wave])));
}

extern "C" void kernel_launch(void* const* d_in, const int* in_sizes, int n_in,
                              void* d_out, int out_size, void* d_ws, size_t ws_size,
                              hipStream_t stream) {
    const float* td_u  = (const float*)d_in[0];
    const float* td_l  = (const float*)d_in[1];
    const float* ld_u  = (const float*)d_in[2];
    const float* ld_l  = (const float*)d_in[3];
    const int*   loc   = (const int*)d_in[4];
    const float* hx    = (const float*)d_in[5];
    const float* Wih   = (const float*)d_in[6];
    const float* Wtu   = (const float*)d_in[7];
    const float* Wtl   = (const float*)d_in[8];
    const float* Wsu   = (const float*)d_in[9];
    const float* Wsl   = (const float*)d_in[10];
    const float* table = (const float*)d_in[11];
    const int L = in_sizes[0];

    float* v   = (float*)d_ws;   // 4*H accumulators
    float* pqu = v + 4 * H;      // p, q, usr (3*H)

    // ws is re-poisoned to 0xAA before every launch — zero the accumulators.
    hipMemsetAsync(v, 0, 4 * H * sizeof(float), stream);

    strnn_gather<<<NBLK, 256, 0, stream>>>(td_u, td_l, ld_u, ld_l, loc, table, v, L);
    strnn_mid<<<64, 256, 0, stream>>>(Wtu, Wtl, Wih, hx, v, pqu);
    strnn_out<<<64, 256, 0, stream>>>(Wsu, Wsl, pqu, (float*)d_out);
}

// Round 7
// 191.684 us; speedup vs baseline: 1.4528x; 1.0178x over previous
//
#include <hip/hip_runtime.h>
#include <math.h>

#define H 256
typedef unsigned long long u64;
typedef unsigned u32;

// ---------------------------------------------------------------------------
// Stage 1 (r3 verbatim): scatter per-event weight components into per-row
// fixed-point bins. ONE u64 atomic carries two 32-bit fixed-point sums
// (2^-24 quantization):
//   U1[r] += (al_q << 32) | be_q
//   U2[r] += (ab_q << 32) | 1        (ab = al*be; low half counts events)
// Max ~15 events/row -> each half < 2^28: no cross-half carry. Exactness
// verified in r3 (absmax 0.0039, pass).
// ---------------------------------------------------------------------------
__global__ __launch_bounds__(256) void strnn_scatter(
    const float* __restrict__ td_u, const float* __restrict__ td_l,
    const float* __restrict__ ld_u, const float* __restrict__ ld_l,
    const int* __restrict__ loc, u64* __restrict__ U1, u64* __restrict__ U2,
    int L)
{
    const int i = blockIdx.x * blockDim.x + threadIdx.x;
    if (i >= L) return;
    const float tu = fminf(fmaxf(td_u[i], 0.f), 1440.f);
    const float tl = fminf(fmaxf(td_l[i], 0.f), 1440.f);
    const float lu = fminf(fmaxf(ld_u[i], 0.f), 40.f);
    const float ll = fminf(fmaxf(ld_l[i], 0.f), 40.f);
    const float al = tu / (tu + tl);
    const float be = lu / (lu + ll);
    const u64 alq = (u64)(unsigned)(al * 16777216.f + 0.5f);
    const u64 beq = (u64)(unsigned)(be * 16777216.f + 0.5f);
    const u64 abq = (u64)(unsigned)(al * be * 16777216.f + 0.5f);
    const int r = loc[i];
    atomicAdd(U1 + r, (alq << 32) | beq);
    atomicAdd(U2 + r, (abq << 32) | 1ull);
}

// ---------------------------------------------------------------------------
// Stage 2: vpart[p][c][h] partial of v[c][h] = sum_r Wc(r)*table[r][h].
// FILL-SHAPED sequential stream: one row per wave (64 lanes x float4 =
// exactly one 1KB row), 4 consecutive rows in flight per wave, minimal
// per-row decode. 1024 blocks x 256 thr = 16 waves/CU, 64KB outstanding/CU.
// Tail: LDS cross-wave reduce, then atomics into one of 8 privatized
// v-planes (128-deep chains/address, burst-safe per r6's lesson).
// ---------------------------------------------------------------------------
__global__ __launch_bounds__(256) void strnn_accum(
    const u64* __restrict__ U1, const u64* __restrict__ U2,
    const float* __restrict__ table, float* __restrict__ vpart, int R)
{
    __shared__ float s_red[4][4][H];   // 16 KB
    const int t    = threadIdx.x;
    const int wave = t >> 6;
    const int lane = t & 63;
    const int wid  = blockIdx.x * 4 + wave;   // global wave id
    const int nw   = gridDim.x * 4;           // total waves

    float4 a0 = {0,0,0,0}, a1 = {0,0,0,0}, a2 = {0,0,0,0}, a3 = {0,0,0,0};
    const float S = 5.9604644775390625e-8f;   // 2^-24

    for (int base = wid * 4; base < R; base += nw * 4) {
        // uniform weight loads for rows base..base+3 (U zero-padded past R)
        const uint4 qa = *(const uint4*)(U1 + base);      // rows +0,+1
        const uint4 qb = *(const uint4*)(U1 + base + 2);  // rows +2,+3
        const uint4 pa = *(const uint4*)(U2 + base);
        const uint4 pb = *(const uint4*)(U2 + base + 2);

        // 4 independent 1KB row loads, issued back-to-back
        float4 e[4];
        #pragma unroll
        for (int u = 0; u < 4; ++u) {
            int r = base + u;
            r = (r < R) ? r : (R - 1);   // clamp addr only; weights are 0 past R
            e[u] = *(const float4*)(table + (size_t)r * H + 4 * lane);
        }

        #pragma unroll
        for (int u = 0; u < 4; ++u) {
            const uint4 q = (u < 2) ? qa : qb;
            const uint4 p = (u < 2) ? pa : pb;
            const float be = (float)((u & 1) ? q.z : q.x) * S;
            const float al = (float)((u & 1) ? q.w : q.y) * S;
            const float ab = (float)((u & 1) ? p.w : p.y) * S;
            const float n  = (float)((u & 1) ? p.z : p.x);
            const float w0 = ab;
            const float w1 = be - ab;
            const float w2 = al - ab;
            const float w3 = (n - be) - w2;
            a0.x = fmaf(w0, e[u].x, a0.x);
            a0.y = fmaf(w0, e[u].y, a0.y);
            a0.z = fmaf(w0, e[u].z, a0.z);
            a0.w = fmaf(w0, e[u].w, a0.w);
            a1.x = fmaf(w1, e[u].x, a1.x);
            a1.y = fmaf(w1, e[u].y, a1.y);
            a1.z = fmaf(w1, e[u].z, a1.z);
            a1.w = fmaf(w1, e[u].w, a1.w);
            a2.x = fmaf(w2, e[u].x, a2.x);
            a2.y = fmaf(w2, e[u].y, a2.y);
            a2.z = fmaf(w2, e[u].z, a2.z);
            a2.w = fmaf(w2, e[u].w, a2.w);
            a3.x = fmaf(w3, e[u].x, a3.x);
            a3.y = fmaf(w3, e[u].y, a3.y);
            a3.z = fmaf(w3, e[u].z, a3.z);
            a3.w = fmaf(w3, e[u].w, a3.w);
        }
    }

    // cross-wave block reduction, then atomics into plane (blockIdx & 7)
    *(float4*)&s_red[wave][0][4 * lane] = a0;
    *(float4*)&s_red[wave][1][4 * lane] = a1;
    *(float4*)&s_red[wave][2][4 * lane] = a2;
    *(float4*)&s_red[wave][3][4 * lane] = a3;
    __syncthreads();
    float* vp = vpart + (size_t)(blockIdx.x & 7) * 4 * H;
    #pragma unroll
    for (int c = 0; c < 4; ++c) {
        float s = s_red[0][c][t] + s_red[1][c][t] + s_red[2][c][t] + s_red[3][c][t];
        atomicAdd(&vp[c * H + t], s);
    }
}

// Kernel 3: one wave per output row h; v materialized from the 8 planes.
__global__ __launch_bounds__(256) void strnn_mid(
    const float* __restrict__ Wtu, const float* __restrict__ Wtl,
    const float* __restrict__ Wih, const float* __restrict__ hx,
    const float* __restrict__ vpart, float* __restrict__ pqu)
{
    const int wave = (blockIdx.x * blockDim.x + threadIdx.x) >> 6;  // = h
    const int lane = threadIdx.x & 63;

    float p = 0.f, q = 0.f, u = 0.f;
    #pragma unroll
    for (int i = 0; i < H; i += 64) {
        const int k = i + lane;
        float v1 = 0.f, v2 = 0.f, v3 = 0.f, v4 = 0.f;
        #pragma unroll
        for (int pl = 0; pl < 8; ++pl) {
            const float* vp = vpart + (size_t)pl * 4 * H;
            v1 += vp[k];
            v2 += vp[H + k];
            v3 += vp[2 * H + k];
            v4 += vp[3 * H + k];
        }
        const float wtu = Wtu[wave * H + k];
        const float wtl = Wtl[wave * H + k];
        p = fmaf(wtu, v1, fmaf(wtl, v2, p));
        q = fmaf(wtu, v3, fmaf(wtl, v4, q));
        u = fmaf(Wih[wave * H + k], hx[k], u);
    }
    #pragma unroll
    for (int off = 32; off > 0; off >>= 1) {
        p += __shfl_down(p, off, 64);
        q += __shfl_down(q, off, 64);
        u += __shfl_down(u, off, 64);
    }
    if (lane == 0) {
        pqu[wave]         = p;
        pqu[H + wave]     = q;
        pqu[2 * H + wave] = u;
    }
}

// Kernel 4: out[h] = sigmoid( Wsu[h,:]·p + Wsl[h,:]·q + u[h] )  (r0 verbatim)
__global__ __launch_bounds__(256) void strnn_out(
    const float* __restrict__ Wsu, const float* __restrict__ Wsl,
    const float* __restrict__ pqu, float* __restrict__ out)
{
    const int wave = (blockIdx.x * blockDim.x + threadIdx.x) >> 6;  // = h
    const int lane = threadIdx.x & 63;
    const float* p = pqu;
    const float* q = pqu + H;
    const float* u = pqu + 2 * H;

    float s = 0.f;
    #pragma unroll
    for (int i = 0; i < H; i += 64) {
        const int k = i + lane;
        s = fmaf(Wsu[wave * H + k], p[k], fmaf(Wsl[wave * H + k], q[k], s));
    }
    #pragma unroll
    for (int off = 32; off > 0; off >>= 1)
        s += __shfl_down(s, off, 64);
    if (lane == 0)
        out[wave] = 1.f / (1.f + expf(-(s + u[wave])));
}

extern "C" void kernel_launch(void* const* d_in, const int* in_sizes, int n_in,
                              void* d_out, int out_size, void* d_ws, size_t ws_size,
                              hipStream_t stream) {
    const float* td_u  = (const float*)d_in[0];
    const float* td_l  = (const float*)d_in[1];
    const float* ld_u  = (const float*)d_in[2];
    const float* ld_l  = (const float*)d_in[3];
    const int*   loc   = (const int*)d_in[4];
    const float* hx    = (const float*)d_in[5];
    const float* Wih   = (const float*)d_in[6];
    const float* Wtu   = (const float*)d_in[7];
    const float* Wtl   = (const float*)d_in[8];
    const float* Wsu   = (const float*)d_in[9];
    const float* Wsl   = (const float*)d_in[10];
    const float* table = (const float*)d_in[11];
    const int L = in_sizes[0];
    const int R = in_sizes[11] / H;            // table rows (LOC_CNT)
    const int Rpad = (R + 15) & ~7;            // zero-padded past R+3

    u64*   U1    = (u64*)d_ws;                 // Σal | Σbe plane
    u64*   U2    = U1 + Rpad;                  // Σ(al·be) | count plane
    float* vpart = (float*)(U2 + Rpad);        // 8 x 4*H privatized planes
    float* pqu   = vpart + 8 * 4 * H;          // p, q, usr (3*H)

    // ws re-poisoned to 0xAA before every launch — zero U planes + vpart.
    hipMemsetAsync(U1, 0,
                   2 * (size_t)Rpad * sizeof(u64) + 8 * 4 * H * sizeof(float),
                   stream);

    strnn_scatter<<<(L + 255) / 256, 256, 0, stream>>>(
        td_u, td_l, ld_u, ld_l, loc, U1, U2, L);
    strnn_accum<<<1024, 256, 0, stream>>>(U1, U2, table, vpart, R);
    strnn_mid<<<64, 256, 0, stream>>>(Wtu, Wtl, Wih, hx, vpart, pqu);
    strnn_out<<<64, 256, 0, stream>>>(Wsu, Wsl, pqu, (float*)d_out);
}

// Round 8
// 183.968 us; speedup vs baseline: 1.5137x; 1.0419x over previous
//
#include <hip/hip_runtime.h>
#include <math.h>

#define H 256
#define TILE 256
#define NBLK 512

typedef float f32x4 __attribute__((ext_vector_type(4)));

// Kernel 1: v[c][h] = sum_l w_c(l) * table[loc[l]][h], c = 0..3
// r0 structure with a SOFTWARE-PIPELINED inner loop: two statically-named
// 8-row buffers (eA/eB); group j+1's loads are issued before group j is
// consumed, so a wave always has 8-16 KB outstanding instead of draining
// to zero at every vmcnt wait (the drain is the theorized 2.7-vs-6.3 TB/s
// gap). Table loads are nontemporal (nt): 134 MB streamed once, no reuse
// worth caching (r5: sorted == unsorted proved dup-caching contributes ~0).
__global__ __launch_bounds__(256) void strnn_gather(
    const float* __restrict__ td_u, const float* __restrict__ td_l,
    const float* __restrict__ ld_u, const float* __restrict__ ld_l,
    const int* __restrict__ loc, const float* __restrict__ table,
    float* __restrict__ v, int L)
{
    __shared__ float4 s_w[TILE];       //  4 KB
    __shared__ int    s_loc[TILE];     //  1 KB
    __shared__ float  s_red[4][4][H];  // 16 KB: [wave][c][col]
    const int t    = threadIdx.x;
    const int wave = t >> 6;
    const int lane = t & 63;

    float4 a0 = {0,0,0,0}, a1 = {0,0,0,0}, a2 = {0,0,0,0}, a3 = {0,0,0,0};

#define ISSUE(buf, jb)                                                        \
    do {                                                                      \
        _Pragma("unroll")                                                     \
        for (int u = 0; u < 8; ++u) {                                         \
            const float* ap =                                                 \
                table + (size_t)s_loc[r0 + (jb) + u] * H + 4 * lane;          \
            buf[u] = __builtin_nontemporal_load((const f32x4*)ap);            \
        }                                                                     \
    } while (0)

#define CONSUME(buf, jb)                                                      \
    do {                                                                      \
        _Pragma("unroll")                                                     \
        for (int u = 0; u < 8; ++u) {                                         \
            const float4 w = s_w[r0 + (jb) + u];                              \
            a0.x = fmaf(w.x, buf[u].x, a0.x);                                 \
            a0.y = fmaf(w.x, buf[u].y, a0.y);                                 \
            a0.z = fmaf(w.x, buf[u].z, a0.z);                                 \
            a0.w = fmaf(w.x, buf[u].w, a0.w);                                 \
            a1.x = fmaf(w.y, buf[u].x, a1.x);                                 \
            a1.y = fmaf(w.y, buf[u].y, a1.y);                                 \
            a1.z = fmaf(w.y, buf[u].z, a1.z);                                 \
            a1.w = fmaf(w.y, buf[u].w, a1.w);                                 \
            a2.x = fmaf(w.z, buf[u].x, a2.x);                                 \
            a2.y = fmaf(w.z, buf[u].y, a2.y);                                 \
            a2.z = fmaf(w.z, buf[u].z, a2.z);                                 \
            a2.w = fmaf(w.z, buf[u].w, a2.w);                                 \
            a3.x = fmaf(w.w, buf[u].x, a3.x);                                 \
            a3.y = fmaf(w.w, buf[u].y, a3.y);                                 \
            a3.z = fmaf(w.w, buf[u].z, a3.z);                                 \
            a3.w = fmaf(w.w, buf[u].w, a3.w);                                 \
        }                                                                     \
    } while (0)

    for (int base = blockIdx.x * TILE; base < L; base += gridDim.x * TILE) {
        const int l = base + t;
        const bool ok = (l < L);
        float tu = ok ? fminf(fmaxf(td_u[l], 0.f), 1440.f) : 1.f;
        float tl = ok ? fminf(fmaxf(td_l[l], 0.f), 1440.f) : 1.f;
        float lu = ok ? fminf(fmaxf(ld_u[l], 0.f), 40.f)   : 1.f;
        float ll = ok ? fminf(fmaxf(ld_l[l], 0.f), 40.f)   : 1.f;
        float al = tu / (tu + tl);
        float be = lu / (lu + ll);
        float w0 = be * al, w1 = be * (1.f - al);
        float w2 = (1.f - be) * al, w3 = (1.f - be) * (1.f - al);
        if (!ok) { w0 = w1 = w2 = w3 = 0.f; }
        s_w[t]   = make_float4(w0, w1, w2, w3);
        s_loc[t] = ok ? loc[l] : 0;
        __syncthreads();

        const int r0 = wave * 64;
        f32x4 eA[8], eB[8];
        ISSUE(eA, 0);
        #pragma unroll
        for (int k = 0; k < 4; ++k) {
            ISSUE(eB, 16 * k + 8);          // next group in flight
            CONSUME(eA, 16 * k);            // waits only on eA (vmcnt(8))
            if (k < 3)
                ISSUE(eA, 16 * k + 16);     // refill while eB in flight
            CONSUME(eB, 16 * k + 8);
        }
        __syncthreads();
    }

#undef ISSUE
#undef CONSUME

    // cross-wave block reduction in LDS, then 4 atomicAdds per thread
    // (512-deep chains overlap trailing blocks; proven ~free in r0)
    *(float4*)&s_red[wave][0][4 * lane] = a0;
    *(float4*)&s_red[wave][1][4 * lane] = a1;
    *(float4*)&s_red[wave][2][4 * lane] = a2;
    *(float4*)&s_red[wave][3][4 * lane] = a3;
    __syncthreads();
    #pragma unroll
    for (int c = 0; c < 4; ++c) {
        float s = s_red[0][c][t] + s_red[1][c][t] + s_red[2][c][t] + s_red[3][c][t];
        atomicAdd(&v[c * H + t], s);
    }
}

// Kernel 2: one wave per output row h (r0 verbatim):
//   p[h] = Wtu[h,:]·v1 + Wtl[h,:]·v2
//   q[h] = Wtu[h,:]·v3 + Wtl[h,:]·v4
//   u[h] = Wih[h,:]·hx
__global__ __launch_bounds__(256) void strnn_mid(
    const float* __restrict__ Wtu, const float* __restrict__ Wtl,
    const float* __restrict__ Wih, const float* __restrict__ hx,
    const float* __restrict__ v, float* __restrict__ pqu)
{
    const int wave = (blockIdx.x * blockDim.x + threadIdx.x) >> 6;  // = h
    const int lane = threadIdx.x & 63;
    const float* v1 = v;
    const float* v2 = v + H;
    const float* v3 = v + 2 * H;
    const float* v4 = v + 3 * H;

    float p = 0.f, q = 0.f, u = 0.f;
    #pragma unroll
    for (int i = 0; i < H; i += 64) {
        const int k = i + lane;
        const float wtu = Wtu[wave * H + k];
        const float wtl = Wtl[wave * H + k];
        p = fmaf(wtu, v1[k], fmaf(wtl, v2[k], p));
        q = fmaf(wtu, v3[k], fmaf(wtl, v4[k], q));
        u = fmaf(Wih[wave * H + k], hx[k], u);
    }
    #pragma unroll
    for (int off = 32; off > 0; off >>= 1) {
        p += __shfl_down(p, off, 64);
        q += __shfl_down(q, off, 64);
        u += __shfl_down(u, off, 64);
    }
    if (lane == 0) {
        pqu[wave]         = p;
        pqu[H + wave]     = q;
        pqu[2 * H + wave] = u;
    }
}

// Kernel 3: out[h] = sigmoid( Wsu[h,:]·p + Wsl[h,:]·q + u[h] )  (r0 verbatim)
__global__ __launch_bounds__(256) void strnn_out(
    const float* __restrict__ Wsu, const float* __restrict__ Wsl,
    const float* __restrict__ pqu, float* __restrict__ out)
{
    const int wave = (blockIdx.x * blockDim.x + threadIdx.x) >> 6;  // = h
    const int lane = threadIdx.x & 63;
    const float* p = pqu;
    const float* q = pqu + H;
    const float* u = pqu + 2 * H;

    float s = 0.f;
    #pragma unroll
    for (int i = 0; i < H; i += 64) {
        const int k = i + lane;
        s = fmaf(Wsu[wave * H + k], p[k], fmaf(Wsl[wave * H + k], q[k], s));
    }
    #pragma unroll
    for (int off = 32; off > 0; off >>= 1)
        s += __shfl_down(s, off, 64);
    if (lane == 0)
        out[wave] = 1.f / (1.f + expf(-(s + u[wave])));
}

extern "C" void kernel_launch(void* const* d_in, const int* in_sizes, int n_in,
                              void* d_out, int out_size, void* d_ws, size_t ws_size,
                              hipStream_t stream) {
    const float* td_u  = (const float*)d_in[0];
    const float* td_l  = (const float*)d_in[1];
    const float* ld_u  = (const float*)d_in[2];
    const float* ld_l  = (const float*)d_in[3];
    const int*   loc   = (const int*)d_in[4];
    const float* hx    = (const float*)d_in[5];
    const float* Wih   = (const float*)d_in[6];
    const float* Wtu   = (const float*)d_in[7];
    const float* Wtl   = (const float*)d_in[8];
    const float* Wsu   = (const float*)d_in[9];
    const float* Wsl   = (const float*)d_in[10];
    const float* table = (const float*)d_in[11];
    const int L = in_sizes[0];

    float* v   = (float*)d_ws;   // 4*H accumulators
    float* pqu = v + 4 * H;      // p, q, usr (3*H)

    // ws is re-poisoned to 0xAA before every launch — zero the accumulators.
    hipMemsetAsync(v, 0, 4 * H * sizeof(float), stream);

    strnn_gather<<<NBLK, 256, 0, stream>>>(td_u, td_l, ld_u, ld_l, loc, table, v, L);
    strnn_mid<<<64, 256, 0, stream>>>(Wtu, Wtl, Wih, hx, v, pqu);
    strnn_out<<<64, 256, 0, stream>>>(Wsu, Wsl, pqu, (float*)d_out);
}